// Round 1
// baseline (489.560 us; speedup 1.0000x reference)
//
#include <hip/hip_runtime.h>
#include <hip/hip_cooperative_groups.h>
#include <hip/hip_bf16.h>
#include <math.h>

#define B_  512
#define DM  1024
#define DI  2048
#define DS  64
#define DTR 64
#define DT  64
#define G_  8
#define E_  4
#define DC  4

namespace cg = cooperative_groups;

typedef __bf16 bf16x8 __attribute__((ext_vector_type(8)));
typedef float  f32x4  __attribute__((ext_vector_type(4)));
typedef unsigned short ushort_t;

__device__ __forceinline__ float bf2f(__hip_bfloat16 h) { return __bfloat162float(h); }
__device__ __forceinline__ __hip_bfloat16 f2bf(float f) { return __float2bfloat16(f); }
__device__ __forceinline__ float sigmoidf_(float x){ return 1.f/(1.f+expf(-x)); }
__device__ __forceinline__ float siluf_(float x){ return x*sigmoidf_(x); }
__device__ __forceinline__ float softplusf_(float x){ return (x>20.f)? x : log1pf(expf(x)); }

__device__ __forceinline__ unsigned int pack2(float a, float b) {
  unsigned short ua = __builtin_bit_cast(unsigned short, (__bf16)a);
  unsigned short ub = __builtin_bit_cast(unsigned short, (__bf16)b);
  return (unsigned int)ua | ((unsigned int)ub << 16);
}
__device__ __forceinline__ uint4 cvt8(float4 v0, float4 v1) {
  uint4 r;
  r.x = pack2(v0.x, v0.y); r.y = pack2(v0.z, v0.w);
  r.z = pack2(v1.x, v1.y); r.w = pack2(v1.z, v1.w);
  return r;
}

enum EpiKind { EPI_PART=0, EPI_G2=1, EPI_G4=2, EPI_BIAS=3 };

struct KParams {
  const float *uk, *tk_c, *tk_p, *W_in, *b_in, *rW, *rb, *freq, *phase, *kanW;
  const float *W_inproj, *conv_w, *conv_b, *W_x, *W_dt, *dt_bias, *W_delta, *D_skip, *W_out;
  __hip_bfloat16 *Pu, *Xs, *Sz, *Yb, *Acat;
  float *bc, *Part, *out_hk, *out_w, *out_mask;
};

// C[m,n] = sum_k A[m,k]*B[n,k], K-contiguous operands. 256 threads = 4 waves
// (2x2), 16x16x32 bf16 MFMA, BK=64, LDS double-buffered; global loads issued
// after the barrier and consumed after the MFMA block so latency overlaps
// compute. BM templated (32 or 64), BN=64 fixed. Entry __syncthreads guards
// LDS reuse across sequential jobs within one (mega-)kernel.
template<int BM, int EK, bool CVTA, bool CVTB, bool B2>
__device__ __forceinline__ void gemm_tile(char* smemc, int bxi, int byi, int bzi,
    const void* __restrict__ Ap, const void* __restrict__ Bp, void* __restrict__ Coutp,
    int Ka, int Kb, int kLen, int N, const KParams& p)
{
  constexpr int BN = 64, BK = 64, SA = 72;      // 144B rows keep 16B align
  constexpr int NA = (BM*BK)/(256*8);
  constexpr int NB = (BN*BK)/(256*8);
  constexpr int WMT = (BM/2)/16;
  constexpr int WNT = (BN/2)/16;
  ushort_t* sA = (ushort_t*)smemc;
  ushort_t* sB = (ushort_t*)(smemc + (size_t)2*BM*SA*sizeof(ushort_t));
  const int tid  = threadIdx.x;
  const int wave = tid >> 6, lane = tid & 63;
  const int wm = wave >> 1, wn = wave & 1;
  const int r = lane & 15, q = lane >> 4;
  const int bm = byi * BM, bn = bxi * BN;
  const int kBase = bzi * kLen;
  const int T = kLen / BK;

  float4 fa[NA][2]; uint4 ua[NA];
  float4 fb[NB][2]; uint4 ub[NB];

  auto loadTiles = [&](int k0) {
    #pragma unroll
    for (int c=0;c<NA;++c) {
      int idx = tid*8 + c*2048; int row = idx>>6, kk = idx&63;
      if constexpr (CVTA) {
        const float* s = (const float*)Ap + (size_t)(bm+row)*Ka + k0 + kk;
        fa[c][0] = *reinterpret_cast<const float4*>(s);
        fa[c][1] = *reinterpret_cast<const float4*>(s+4);
      } else {
        const __hip_bfloat16* s = (const __hip_bfloat16*)Ap + (size_t)(bm+row)*Ka + k0 + kk;
        ua[c] = *reinterpret_cast<const uint4*>(s);
      }
    }
    #pragma unroll
    for (int c=0;c<NB;++c) {
      int idx = tid*8 + c*2048; int row = idx>>6, kk = idx&63;
      if constexpr (B2) {
        const float* bb = (k0==0) ? (const float*)Bp : p.W_delta;  // [W_dt | W_delta]
        const float* s = bb + (size_t)(bn+row)*Kb + kk;
        fb[c][0] = *reinterpret_cast<const float4*>(s);
        fb[c][1] = *reinterpret_cast<const float4*>(s+4);
      } else if constexpr (CVTB) {
        const float* s = (const float*)Bp + (size_t)(bn+row)*Kb + k0 + kk;
        fb[c][0] = *reinterpret_cast<const float4*>(s);
        fb[c][1] = *reinterpret_cast<const float4*>(s+4);
      } else {
        const __hip_bfloat16* s = (const __hip_bfloat16*)Bp + (size_t)(bn+row)*Kb + k0 + kk;
        ub[c] = *reinterpret_cast<const uint4*>(s);
      }
    }
  };
  auto writeTiles = [&](int buf) {
    #pragma unroll
    for (int c=0;c<NA;++c) {
      int idx = tid*8 + c*2048; int row = idx>>6, kk = idx&63;
      uint4 v; if constexpr (CVTA) v = cvt8(fa[c][0], fa[c][1]); else v = ua[c];
      *reinterpret_cast<uint4*>(&sA[buf*(BM*SA) + row*SA + kk]) = v;
    }
    #pragma unroll
    for (int c=0;c<NB;++c) {
      int idx = tid*8 + c*2048; int row = idx>>6, kk = idx&63;
      uint4 v; if constexpr (CVTB || B2) v = cvt8(fb[c][0], fb[c][1]); else v = ub[c];
      *reinterpret_cast<uint4*>(&sB[buf*(BN*SA) + row*SA + kk]) = v;
    }
  };

  f32x4 acc[WMT][WNT];
  #pragma unroll
  for (int i=0;i<WMT;++i)
    #pragma unroll
    for (int j=0;j<WNT;++j) acc[i][j] = (f32x4){0.f,0.f,0.f,0.f};

  __syncthreads();                    // LDS reuse guard (prev job / prev stage)
  loadTiles(kBase);
  writeTiles(0);
  for (int t=0; t<T; ++t) {
    __syncthreads();
    const int cur = t & 1;
    if (t+1 < T) loadTiles(kBase + (t+1)*BK);   // overlaps MFMA below
    #pragma unroll
    for (int ks=0; ks<2; ++ks) {
      bf16x8 af[WMT], bfr[WNT];
      #pragma unroll
      for (int mt=0; mt<WMT; ++mt)
        af[mt] = *reinterpret_cast<const bf16x8*>(&sA[cur*(BM*SA) + (wm*(BM/2)+mt*16+r)*SA + ks*32 + q*8]);
      #pragma unroll
      for (int nt=0; nt<WNT; ++nt)
        bfr[nt] = *reinterpret_cast<const bf16x8*>(&sB[cur*(BN*SA) + (wn*(BN/2)+nt*16+r)*SA + ks*32 + q*8]);
      #pragma unroll
      for (int mt=0; mt<WMT; ++mt)
        #pragma unroll
        for (int nt=0; nt<WNT; ++nt)
          acc[mt][nt] = __builtin_amdgcn_mfma_f32_16x16x32_bf16(af[mt], bfr[nt], acc[mt][nt], 0,0,0);
    }
    if (t+1 < T) writeTiles(cur ^ 1);
  }

  #pragma unroll
  for (int mt=0; mt<WMT; ++mt) {
    #pragma unroll
    for (int nt=0; nt<WNT; ++nt) {
      #pragma unroll
      for (int i=0;i<4;++i) {
        int grow = bm + wm*(BM/2) + mt*16 + q*4 + i;
        int gcol = bn + wn*(BN/2) + nt*16 + r;
        float v = acc[mt][nt][i];
        if constexpr (EK == EPI_PART) {
          float* P = (float*)Coutp + (size_t)bzi * ((size_t)B_*N);
          P[(size_t)grow*N + gcol] = v;
        } else if constexpr (EK == EPI_BIAS) {
          p.Pu[(size_t)grow*N + gcol] = f2bf(v + p.b_in[gcol]);
        } else if constexpr (EK == EPI_G2) {
          if (gcol < DI) {  // x half: conv last tap + silu
            float xc = v * p.conv_w[gcol*DC + (DC-1)] + p.conv_b[gcol];
            p.Xs[(size_t)grow*DI + gcol] = f2bf(siluf_(xc));
          } else {          // z half: silu(z)
            p.Sz[(size_t)grow*DI + (gcol - DI)] = f2bf(siluf_(v));
          }
        } else {            // EPI_G4
          float dt  = softplusf_(v + p.dt_bias[gcol]);
          float xsv = bf2f(p.Xs[(size_t)grow*DI + gcol]);
          float szv = bf2f(p.Sz[(size_t)grow*DI + gcol]);
          float y = (dt * xsv * p.bc[grow] + p.D_skip[gcol] * xsv) * szv;
          p.Yb[(size_t)grow*DI + gcol] = f2bf(y);
        }
      }
    }
  }
}

// ---- routing / kan ----

__device__ __forceinline__ void route(float t, const float* rW, const float* rb,
                                      float* w, float* mask, float* wn)
{
  float l[E_];
  float m = -1e30f;
  for (int e=0;e<E_;++e){ l[e] = t*rW[e] + rb[e]; m = fmaxf(m, l[e]); }
  float s = 0.f;
  for (int e=0;e<E_;++e){ w[e] = expf(l[e]-m); s += w[e]; }
  for (int e=0;e<E_;++e) w[e] /= s;
  int i1 = 0;
  for (int e=1;e<E_;++e) if (w[e] > w[i1]) i1 = e;
  int i2 = -1;
  for (int e=0;e<E_;++e) if (e != i1 && (i2 < 0 || w[e] > w[i2])) i2 = e;
  float ssel = w[i1] + w[i2] + 1e-8f;
  for (int e=0;e<E_;++e){
    float mk = (e==i1 || e==i2) ? 1.f : 0.f;
    mask[e] = mk;
    wn[e] = mk * w[e] / ssel;
  }
}

// One job = 4 batch rows, one per wave. dphi slices live in the shared scratch.
__device__ __forceinline__ void kan_job(char* smemc, int job, const KParams& p)
{
  float* dphi = (float*)smemc;                  // 4 waves x 512 floats = 8 KB
  const int wv = threadIdx.x >> 6, lane = threadIdx.x & 63;
  const int b = job*4 + wv;
  __syncthreads();                              // LDS reuse guard
  {
    float t  = p.tk_c[b];
    float tp = p.tk_p[b];
    float w_c[E_], mk_c[E_], wn_c[E_];
    float w_p[E_], mk_p[E_], wn_p[E_];
    route(t,  p.rW, p.rb, w_c, mk_c, wn_c);
    route(tp, p.rW, p.rb, w_p, mk_p, wn_p);
    if (lane < E_) {
      p.out_w[b*E_ + lane]    = w_c[lane];
      p.out_mask[b*E_ + lane] = mk_c[lane];
    }
    float ec = 0.f, epv = 0.f;
    #pragma unroll
    for (int e=0;e<E_;++e) {
      float f  = p.freq[e*DT + lane];
      float ph = p.phase[e*DT + lane];
      ec  += wn_c[e] * sinf(t*f + ph);
      epv += wn_p[e] * sinf(tp*f + ph);
    }
    const float h = 2.f/(G_-1);
    #pragma unroll
    for (int g=0; g<G_; ++g) {
      float gr = -1.f + g*h;
      float a  = (ec - gr)/h;
      float bb = (epv - gr)/h;
      dphi[wv*512 + lane*G_ + g] = expf(-a*a) - expf(-bb*bb);
    }
  }
  __syncthreads();
  {
    float accv = 0.f;
    const float* kw = p.kanW + (size_t)lane*(DT*G_);
    const float* dd = dphi + wv*512;
    #pragma unroll 4
    for (int j=0;j<DT*G_;j+=4) {
      float4 kv = *reinterpret_cast<const float4*>(kw + j);
      float4 dv = *reinterpret_cast<const float4*>(dd + j);   // LDS broadcast
      accv += kv.x*dv.x + kv.y*dv.y + kv.z*dv.z + kv.w*dv.w;
    }
    p.Acat[b*128 + 64 + lane] = f2bf(accv);
  }
}

// x_dbl reduce (8 splits): cols<64 -> Acat[:,0:64] bf16 (dt_r); cols 64..191
// are B,C — stash in LDS, bc[row] = dot(B,C) via wave reduce. One row per wg.
__device__ __forceinline__ void r3_job(char* smemc, int row, const KParams& p)
{
  float* sbc = (float*)smemc;                   // 128 floats
  const int col = threadIdx.x;                  // 256 threads, 192 active
  __syncthreads();                              // LDS reuse guard
  float s = 0.f;
  if (col < 192) {
    #pragma unroll
    for (int k=0;k<8;++k) s += p.Part[(size_t)k*((size_t)B_*192) + row*192 + col];
    if (col < 64) p.Acat[row*128 + col] = f2bf(s);
    else          sbc[col-64] = s;
  }
  __syncthreads();
  if (col < 64) {
    float pval = sbc[col] * sbc[col+64];
    #pragma unroll
    for (int off=32; off; off>>=1) pval += __shfl_down(pval, off);
    if (col == 0) p.bc[row] = pval;
  }
}

// ---- the whole pipeline as one cooperative kernel ----
// 512 wgs x 256 thr, 2 wg/CU co-resident (36.8 KB LDS, launch_bounds caps VGPR).
// 5 grid syncs replace 8 inter-kernel dependencies.
__global__ __launch_bounds__(256, 2)
void mega_kernel(KParams p)
{
  __shared__ __align__(16) char smem[2*64*72*2 + 2*64*72*2];   // 36864 B
  cg::grid_group grid = cg::this_grid();
  const int wg = blockIdx.x;

  // S0: G1 pu = uk@W_in^T + b_in (128 tiles, un-split, bias fused)
  //  || mote+kan (128 jobs x 4 rows) — independent, disjoint wgs
  if (wg < 128) {
    gemm_tile<64,EPI_BIAS,true,true,false>(smem, wg&15, wg>>4, 0,
        p.uk, p.W_in, nullptr, DM, DM, DM, DM, p);
  } else if (wg < 256) {
    kan_job(smem, wg-128, p);
  }
  grid.sync();

  // S1: xz = pu @ W_inproj^T (512x4096x1024), conv+silu / silu(z) fused. 512 jobs.
  gemm_tile<64,EPI_G2,false,true,false>(smem, wg&63, wg>>6, 0,
      p.Pu, p.W_inproj, nullptr, DM, DM, DM, 2*DI, p);
  grid.sync();

  // S2: x_dbl = xs @ W_x^T (512x192x2048), split-K x8 -> partials. 384 jobs.
  if (wg < 384) {
    const int bx = wg % 3, rem = wg / 3;
    gemm_tile<32,EPI_PART,false,true,false>(smem, bx, rem&15, rem>>4,
        p.Xs, p.W_x, p.Part, DI, DI, 256, 192, p);
  }
  grid.sync();

  // S3: reduce partials -> Acat[:,0:64], bc. 512 jobs.
  r3_job(smem, wg, p);
  grid.sync();

  // S4: dt GEMM (512x2048x128, B=[W_dt|W_delta]) + softplus + y fusion. 512 jobs.
  gemm_tile<32,EPI_G4,false,true,true>(smem, wg&31, wg>>5, 0,
      p.Acat, p.W_dt, nullptr, 128, 64, 128, DI, p);
  grid.sync();

  // S5: hk = y @ W_out^T (512x1024x2048), un-split, f32 out. 128 jobs.
  if (wg < 128) {
    gemm_tile<64,EPI_PART,false,true,false>(smem, wg&15, wg>>4, 0,
        p.Yb, p.W_out, p.out_hk, DI, DI, DI, DM, p);
  }
}

// ---- fallback wrappers (plain launches of the same device code) ----

template<int BM, int EK, bool CVTA, bool CVTB, bool B2>
__global__ __launch_bounds__(256)
void gemm_wrap(const void* __restrict__ Ap, const void* __restrict__ Bp,
               void* __restrict__ Coutp, int Ka, int Kb, int kLen, int N, KParams p)
{
  __shared__ __align__(16) char smem[2*64*72*2 + 2*64*72*2];
  gemm_tile<BM,EK,CVTA,CVTB,B2>(smem, blockIdx.x, blockIdx.y, blockIdx.z,
                                Ap, Bp, Coutp, Ka, Kb, kLen, N, p);
}

__global__ __launch_bounds__(256)
void kan_wrap(KParams p)
{
  __shared__ __align__(16) char smem[8192];
  kan_job(smem, blockIdx.x, p);
}

__global__ __launch_bounds__(256)
void r3_wrap(KParams p)
{
  __shared__ __align__(16) char smem[512];
  r3_job(smem, blockIdx.x, p);
}

extern "C" void kernel_launch(void* const* d_in, const int* in_sizes, int n_in,
                              void* d_out, int out_size, void* d_ws, size_t ws_size,
                              hipStream_t stream)
{
  KParams p;
  p.uk       = (const float*)d_in[0];
  p.tk_c     = (const float*)d_in[1];
  p.tk_p     = (const float*)d_in[2];
  p.W_in     = (const float*)d_in[3];
  p.b_in     = (const float*)d_in[4];
  p.rW       = (const float*)d_in[5];
  p.rb       = (const float*)d_in[6];
  p.freq     = (const float*)d_in[7];
  p.phase    = (const float*)d_in[8];
  p.kanW     = (const float*)d_in[9];
  p.W_inproj = (const float*)d_in[10];
  p.conv_w   = (const float*)d_in[11];
  p.conv_b   = (const float*)d_in[12];
  p.W_x      = (const float*)d_in[13];
  p.W_dt     = (const float*)d_in[14];
  p.dt_bias  = (const float*)d_in[15];
  p.W_delta  = (const float*)d_in[16];
  p.D_skip   = (const float*)d_in[18];
  p.W_out    = (const float*)d_in[19];

  char* ws = (char*)d_ws;
  p.Pu   = (__hip_bfloat16*)(ws);                                // 1 MB
  p.Xs   = (__hip_bfloat16*)(ws + (size_t)(1<<20));              // 2 MB
  p.Sz   = (__hip_bfloat16*)(ws + (size_t)3*(1<<20));            // 2 MB
  p.Yb   = (__hip_bfloat16*)(ws + (size_t)5*(1<<20));            // 2 MB
  p.Acat = (__hip_bfloat16*)(ws + (size_t)7*(1<<20));            // 128 KB
  p.bc   = (float*)         (ws + (size_t)7*(1<<20) + (128<<10));// 2 KB
  p.Part = (float*)         (ws + (size_t)8*(1<<20));            // 3 MB

  p.out_hk   = (float*)d_out;
  p.out_w    = p.out_hk + (size_t)B_*DM;
  p.out_mask = p.out_w  + (size_t)B_*E_;

  void* kargs[] = { &p };
  hipError_t st = hipLaunchCooperativeKernel((void*)mega_kernel,
                                             dim3(512), dim3(256), kargs, 0, stream);
  if (st != hipSuccess) {
    // fallback: same device code as 7 plain launches
    kan_wrap<<<dim3(128), 256, 0, stream>>>(p);
    gemm_wrap<64,EPI_BIAS,true,true,false><<<dim3(16,8), 256, 0, stream>>>(
        p.uk, p.W_in, nullptr, DM, DM, DM, DM, p);
    gemm_wrap<64,EPI_G2,false,true,false><<<dim3(64,8), 256, 0, stream>>>(
        p.Pu, p.W_inproj, nullptr, DM, DM, DM, 2*DI, p);
    gemm_wrap<32,EPI_PART,false,true,false><<<dim3(3,16,8), 256, 0, stream>>>(
        p.Xs, p.W_x, p.Part, DI, DI, 256, 192, p);
    r3_wrap<<<dim3(512), 256, 0, stream>>>(p);
    gemm_wrap<32,EPI_G4,false,true,true><<<dim3(32,16), 256, 0, stream>>>(
        p.Acat, p.W_dt, nullptr, 128, 64, 128, DI, p);
    gemm_wrap<64,EPI_PART,false,true,false><<<dim3(16,8), 256, 0, stream>>>(
        p.Yb, p.W_out, p.out_hk, DI, DI, DI, DM, p);
  }
}

// Round 2
// 188.646 us; speedup vs baseline: 2.5951x; 2.5951x over previous
//
#include <hip/hip_runtime.h>
#include <hip/hip_bf16.h>
#include <math.h>

#define B_  512
#define DM  1024
#define DI  2048
#define DS  64
#define DTR 64
#define DT  64
#define G_  8
#define E_  4
#define DC  4

typedef __bf16 bf16x8 __attribute__((ext_vector_type(8)));
typedef float  f32x4  __attribute__((ext_vector_type(4)));
typedef unsigned short ushort_t;

__device__ __forceinline__ float bf2f(__hip_bfloat16 h) { return __bfloat162float(h); }
__device__ __forceinline__ __hip_bfloat16 f2bf(float f) { return __float2bfloat16(f); }
__device__ __forceinline__ float sigmoidf_(float x){ return 1.f/(1.f+expf(-x)); }
__device__ __forceinline__ float siluf_(float x){ return x*sigmoidf_(x); }
__device__ __forceinline__ float softplusf_(float x){ return (x>20.f)? x : log1pf(expf(x)); }

__device__ __forceinline__ unsigned int pack2(float a, float b) {
  unsigned short ua = __builtin_bit_cast(unsigned short, (__bf16)a);
  unsigned short ub = __builtin_bit_cast(unsigned short, (__bf16)b);
  return (unsigned int)ua | ((unsigned int)ub << 16);
}
__device__ __forceinline__ uint4 cvt8(float4 v0, float4 v1) {
  uint4 r;
  r.x = pack2(v0.x, v0.y); r.y = pack2(v0.z, v0.w);
  r.z = pack2(v1.x, v1.y); r.w = pack2(v1.z, v1.w);
  return r;
}

enum EpiKind { EPI_PART=0, EPI_G2=1, EPI_G4=2, EPI_BIAS=3 };

struct KParams {
  const float *uk, *tk_c, *tk_p, *W_in, *b_in, *rW, *rb, *freq, *phase, *kanW;
  const float *W_inproj, *conv_w, *conv_b, *W_x, *W_dt, *dt_bias, *W_delta, *D_skip, *W_out;
  __hip_bfloat16 *Pu, *Xs, *Sz, *Yb, *Acat;
  float *bc, *Part, *out_hk, *out_w, *out_mask;
};

// C[m,n] = sum_k A[m,k]*B[n,k], K-contiguous operands. 256 threads = 4 waves
// (2x2), 16x16x32 bf16 MFMA, BK=64, LDS double-buffered; global loads issued
// after the barrier and consumed after the MFMA block so latency overlaps
// compute. BM templated (32 or 64), BN=64 fixed.
template<int BM, int EK, bool CVTA, bool CVTB, bool B2>
__device__ __forceinline__ void gemm_tile(char* smemc, int bxi, int byi, int bzi,
    const void* __restrict__ Ap, const void* __restrict__ Bp, void* __restrict__ Coutp,
    int Ka, int Kb, int kLen, int N, const KParams& p)
{
  constexpr int BN = 64, BK = 64, SA = 72;      // 144B rows keep 16B align
  constexpr int NA = (BM*BK)/(256*8);
  constexpr int NB = (BN*BK)/(256*8);
  constexpr int WMT = (BM/2)/16;
  constexpr int WNT = (BN/2)/16;
  ushort_t* sA = (ushort_t*)smemc;
  ushort_t* sB = (ushort_t*)(smemc + (size_t)2*BM*SA*sizeof(ushort_t));
  const int tid  = threadIdx.x;
  const int wave = tid >> 6, lane = tid & 63;
  const int wm = wave >> 1, wn = wave & 1;
  const int r = lane & 15, q = lane >> 4;
  const int bm = byi * BM, bn = bxi * BN;
  const int kBase = bzi * kLen;
  const int T = kLen / BK;

  float4 fa[NA][2]; uint4 ua[NA];
  float4 fb[NB][2]; uint4 ub[NB];

  auto loadTiles = [&](int k0) {
    #pragma unroll
    for (int c=0;c<NA;++c) {
      int idx = tid*8 + c*2048; int row = idx>>6, kk = idx&63;
      if constexpr (CVTA) {
        const float* s = (const float*)Ap + (size_t)(bm+row)*Ka + k0 + kk;
        fa[c][0] = *reinterpret_cast<const float4*>(s);
        fa[c][1] = *reinterpret_cast<const float4*>(s+4);
      } else {
        const __hip_bfloat16* s = (const __hip_bfloat16*)Ap + (size_t)(bm+row)*Ka + k0 + kk;
        ua[c] = *reinterpret_cast<const uint4*>(s);
      }
    }
    #pragma unroll
    for (int c=0;c<NB;++c) {
      int idx = tid*8 + c*2048; int row = idx>>6, kk = idx&63;
      if constexpr (B2) {
        const float* bb = (k0==0) ? (const float*)Bp : p.W_delta;  // [W_dt | W_delta]
        const float* s = bb + (size_t)(bn+row)*Kb + kk;
        fb[c][0] = *reinterpret_cast<const float4*>(s);
        fb[c][1] = *reinterpret_cast<const float4*>(s+4);
      } else if constexpr (CVTB) {
        const float* s = (const float*)Bp + (size_t)(bn+row)*Kb + k0 + kk;
        fb[c][0] = *reinterpret_cast<const float4*>(s);
        fb[c][1] = *reinterpret_cast<const float4*>(s+4);
      } else {
        const __hip_bfloat16* s = (const __hip_bfloat16*)Bp + (size_t)(bn+row)*Kb + k0 + kk;
        ub[c] = *reinterpret_cast<const uint4*>(s);
      }
    }
  };
  auto writeTiles = [&](int buf) {
    #pragma unroll
    for (int c=0;c<NA;++c) {
      int idx = tid*8 + c*2048; int row = idx>>6, kk = idx&63;
      uint4 v; if constexpr (CVTA) v = cvt8(fa[c][0], fa[c][1]); else v = ua[c];
      *reinterpret_cast<uint4*>(&sA[buf*(BM*SA) + row*SA + kk]) = v;
    }
    #pragma unroll
    for (int c=0;c<NB;++c) {
      int idx = tid*8 + c*2048; int row = idx>>6, kk = idx&63;
      uint4 v; if constexpr (CVTB || B2) v = cvt8(fb[c][0], fb[c][1]); else v = ub[c];
      *reinterpret_cast<uint4*>(&sB[buf*(BN*SA) + row*SA + kk]) = v;
    }
  };

  f32x4 acc[WMT][WNT];
  #pragma unroll
  for (int i=0;i<WMT;++i)
    #pragma unroll
    for (int j=0;j<WNT;++j) acc[i][j] = (f32x4){0.f,0.f,0.f,0.f};

  loadTiles(kBase);
  writeTiles(0);
  for (int t=0; t<T; ++t) {
    __syncthreads();
    const int cur = t & 1;
    if (t+1 < T) loadTiles(kBase + (t+1)*BK);   // overlaps MFMA below
    #pragma unroll
    for (int ks=0; ks<2; ++ks) {
      bf16x8 af[WMT], bfr[WNT];
      #pragma unroll
      for (int mt=0; mt<WMT; ++mt)
        af[mt] = *reinterpret_cast<const bf16x8*>(&sA[cur*(BM*SA) + (wm*(BM/2)+mt*16+r)*SA + ks*32 + q*8]);
      #pragma unroll
      for (int nt=0; nt<WNT; ++nt)
        bfr[nt] = *reinterpret_cast<const bf16x8*>(&sB[cur*(BN*SA) + (wn*(BN/2)+nt*16+r)*SA + ks*32 + q*8]);
      #pragma unroll
      for (int mt=0; mt<WMT; ++mt)
        #pragma unroll
        for (int nt=0; nt<WNT; ++nt)
          acc[mt][nt] = __builtin_amdgcn_mfma_f32_16x16x32_bf16(af[mt], bfr[nt], acc[mt][nt], 0,0,0);
    }
    if (t+1 < T) writeTiles(cur ^ 1);
  }

  #pragma unroll
  for (int mt=0; mt<WMT; ++mt) {
    #pragma unroll
    for (int nt=0; nt<WNT; ++nt) {
      #pragma unroll
      for (int i=0;i<4;++i) {
        int grow = bm + wm*(BM/2) + mt*16 + q*4 + i;
        int gcol = bn + wn*(BN/2) + nt*16 + r;
        float v = acc[mt][nt][i];
        if constexpr (EK == EPI_PART) {
          float* P = (float*)Coutp + (size_t)bzi * ((size_t)B_*N);
          P[(size_t)grow*N + gcol] = v;
        } else if constexpr (EK == EPI_BIAS) {
          p.Pu[(size_t)grow*N + gcol] = f2bf(v + p.b_in[gcol]);
        } else if constexpr (EK == EPI_G2) {
          if (gcol < DI) {  // x half: conv last tap + silu
            float xc = v * p.conv_w[gcol*DC + (DC-1)] + p.conv_b[gcol];
            p.Xs[(size_t)grow*DI + gcol] = f2bf(siluf_(xc));
          } else {          // z half: silu(z)
            p.Sz[(size_t)grow*DI + (gcol - DI)] = f2bf(siluf_(v));
          }
        } else {            // EPI_G4
          float dt  = softplusf_(v + p.dt_bias[gcol]);
          float xsv = bf2f(p.Xs[(size_t)grow*DI + gcol]);
          float szv = bf2f(p.Sz[(size_t)grow*DI + gcol]);
          float y = (dt * xsv * p.bc[grow] + p.D_skip[gcol] * xsv) * szv;
          p.Yb[(size_t)grow*DI + gcol] = f2bf(y);
        }
      }
    }
  }
}

// ---- routing / kan ----

__device__ __forceinline__ void route(float t, const float* rW, const float* rb,
                                      float* w, float* mask, float* wn)
{
  float l[E_];
  float m = -1e30f;
  for (int e=0;e<E_;++e){ l[e] = t*rW[e] + rb[e]; m = fmaxf(m, l[e]); }
  float s = 0.f;
  for (int e=0;e<E_;++e){ w[e] = expf(l[e]-m); s += w[e]; }
  for (int e=0;e<E_;++e) w[e] /= s;
  int i1 = 0;
  for (int e=1;e<E_;++e) if (w[e] > w[i1]) i1 = e;
  int i2 = -1;
  for (int e=0;e<E_;++e) if (e != i1 && (i2 < 0 || w[e] > w[i2])) i2 = e;
  float ssel = w[i1] + w[i2] + 1e-8f;
  for (int e=0;e<E_;++e){
    float mk = (e==i1 || e==i2) ? 1.f : 0.f;
    mask[e] = mk;
    wn[e] = mk * w[e] / ssel;
  }
}

// One job = 4 batch rows, one per wave. dphi slices live in the shared scratch.
__device__ __forceinline__ void kan_job(char* smemc, int job, const KParams& p)
{
  float* dphi = (float*)smemc;                  // 4 waves x 512 floats = 8 KB
  const int wv = threadIdx.x >> 6, lane = threadIdx.x & 63;
  const int b = job*4 + wv;
  {
    float t  = p.tk_c[b];
    float tp = p.tk_p[b];
    float w_c[E_], mk_c[E_], wn_c[E_];
    float w_p[E_], mk_p[E_], wn_p[E_];
    route(t,  p.rW, p.rb, w_c, mk_c, wn_c);
    route(tp, p.rW, p.rb, w_p, mk_p, wn_p);
    if (lane < E_) {
      p.out_w[b*E_ + lane]    = w_c[lane];
      p.out_mask[b*E_ + lane] = mk_c[lane];
    }
    float ec = 0.f, epv = 0.f;
    #pragma unroll
    for (int e=0;e<E_;++e) {
      float f  = p.freq[e*DT + lane];
      float ph = p.phase[e*DT + lane];
      ec  += wn_c[e] * sinf(t*f + ph);
      epv += wn_p[e] * sinf(tp*f + ph);
    }
    const float h = 2.f/(G_-1);
    #pragma unroll
    for (int g=0; g<G_; ++g) {
      float gr = -1.f + g*h;
      float a  = (ec - gr)/h;
      float bb = (epv - gr)/h;
      dphi[wv*512 + lane*G_ + g] = expf(-a*a) - expf(-bb*bb);
    }
  }
  __syncthreads();
  {
    float accv = 0.f;
    const float* kw = p.kanW + (size_t)lane*(DT*G_);
    const float* dd = dphi + wv*512;
    #pragma unroll 4
    for (int j=0;j<DT*G_;j+=4) {
      float4 kv = *reinterpret_cast<const float4*>(kw + j);
      float4 dv = *reinterpret_cast<const float4*>(dd + j);   // LDS broadcast
      accv += kv.x*dv.x + kv.y*dv.y + kv.z*dv.z + kv.w*dv.w;
    }
    p.Acat[b*128 + 64 + lane] = f2bf(accv);
  }
}

// ---- kernels ----

// G1 (un-split, bias fused) + mote/kan in one launch on disjoint wg ranges.
// wg<256: 16x16 tiles of pu = uk@W_in^T + b_in (m-fastest order); wg>=256: kan.
__global__ __launch_bounds__(256)
void g1kan_kernel(KParams p)
{
  __shared__ __align__(16) char smem[(2*32*72 + 2*64*72)*2];   // 27648 B
  const int id = blockIdx.x;
  if (id < 256) {
    const int byi = id & 15, bxi = id >> 4;     // m-fastest: share B panel
    gemm_tile<32,EPI_BIAS,true,true,false>(smem, bxi, byi, 0,
        p.uk, p.W_in, nullptr, DM, DM, DM, DM, p);
  } else {
    kan_job(smem, id - 256, p);
  }
}

// Generic GEMM wrapper, m-fastest flattened wg order (M-tiles of one B panel
// get consecutive ids -> concurrent, B panel stays hot in L2/L3).
template<int BM, int MT, int NT, int EK, bool CVTA, bool CVTB, bool B2>
__global__ __launch_bounds__(256)
void gemm_mfirst(const void* __restrict__ Ap, const void* __restrict__ Bp,
                 void* __restrict__ Coutp, int Ka, int Kb, int kLen, int N, KParams p)
{
  __shared__ __align__(16) char smem[(2*BM*72 + 2*64*72)*2];
  const int id = blockIdx.x;
  const int byi = id % MT;
  const int rem = id / MT;
  const int bxi = rem % NT;
  const int bzi = rem / NT;
  gemm_tile<BM,EK,CVTA,CVTB,B2>(smem, bxi, byi, bzi, Ap, Bp, Coutp, Ka, Kb, kLen, N, p);
}

// x_dbl reduce (8 splits): cols<64 -> Acat[:,0:64] bf16 (dt_r); cols 64..191
// are B,C — stash in LDS, bc[row] = dot(B,C) via wave reduce. One row per wg.
__global__ __launch_bounds__(256)
void r3_kernel(KParams p)
{
  __shared__ float sbc[128];
  const int row = blockIdx.x, col = threadIdx.x;   // 256 thr, 192 active
  float s = 0.f;
  if (col < 192) {
    #pragma unroll
    for (int k=0;k<8;++k) s += p.Part[(size_t)k*((size_t)B_*192) + row*192 + col];
    if (col < 64) p.Acat[row*128 + col] = f2bf(s);
    else          sbc[col-64] = s;
  }
  __syncthreads();
  if (col < 64) {
    float pval = sbc[col] * sbc[col+64];
    #pragma unroll
    for (int off=32; off; off>>=1) pval += __shfl_down(pval, off);
    if (col == 0) p.bc[row] = pval;
  }
}

// hk = sum_{s<4} part[s]  (f32 out)
__global__ __launch_bounds__(256)
void reduce_plain_kernel(KParams p)
{
  const int i = blockIdx.x*256 + threadIdx.x;
  const int total = B_*DM/4;
  const float4* pp = (const float4*)p.Part;
  float4 s = pp[i];
  #pragma unroll
  for (int k=1;k<4;++k){ float4 t = pp[i + k*total]; s.x+=t.x; s.y+=t.y; s.z+=t.z; s.w+=t.w; }
  ((float4*)p.out_hk)[i] = s;
}

extern "C" void kernel_launch(void* const* d_in, const int* in_sizes, int n_in,
                              void* d_out, int out_size, void* d_ws, size_t ws_size,
                              hipStream_t stream)
{
  KParams p;
  p.uk       = (const float*)d_in[0];
  p.tk_c     = (const float*)d_in[1];
  p.tk_p     = (const float*)d_in[2];
  p.W_in     = (const float*)d_in[3];
  p.b_in     = (const float*)d_in[4];
  p.rW       = (const float*)d_in[5];
  p.rb       = (const float*)d_in[6];
  p.freq     = (const float*)d_in[7];
  p.phase    = (const float*)d_in[8];
  p.kanW     = (const float*)d_in[9];
  p.W_inproj = (const float*)d_in[10];
  p.conv_w   = (const float*)d_in[11];
  p.conv_b   = (const float*)d_in[12];
  p.W_x      = (const float*)d_in[13];
  p.W_dt     = (const float*)d_in[14];
  p.dt_bias  = (const float*)d_in[15];
  p.W_delta  = (const float*)d_in[16];
  p.D_skip   = (const float*)d_in[18];
  p.W_out    = (const float*)d_in[19];

  char* ws = (char*)d_ws;
  p.Pu   = (__hip_bfloat16*)(ws);                                // 1 MB
  p.Xs   = (__hip_bfloat16*)(ws + (size_t)(1<<20));              // 2 MB
  p.Sz   = (__hip_bfloat16*)(ws + (size_t)3*(1<<20));            // 2 MB
  p.Yb   = (__hip_bfloat16*)(ws + (size_t)5*(1<<20));            // 2 MB
  p.Acat = (__hip_bfloat16*)(ws + (size_t)7*(1<<20));            // 128 KB
  p.bc   = (float*)         (ws + (size_t)7*(1<<20) + (128<<10));// 2 KB
  p.Part = (float*)         (ws + (size_t)8*(1<<20));            // 8 MB

  p.out_hk   = (float*)d_out;
  p.out_w    = p.out_hk + (size_t)B_*DM;
  p.out_mask = p.out_w  + (size_t)B_*E_;

  // K1: G1 (un-split, bias fused, 256 tiles) + mote/kan (128 jobs)
  g1kan_kernel<<<dim3(384), 256, 0, stream>>>(p);

  // G2: xz = pu @ W_inproj^T (512x4096x1024), BM=64, conv+silu / silu fused
  gemm_mfirst<64,8,64,EPI_G2,false,true,false><<<dim3(512), 256, 0, stream>>>(
      p.Pu, p.W_inproj, nullptr, DM, DM, DM, 2*DI, p);

  // G3: x_dbl = xs @ W_x^T (512x192x2048), split-K x8 -> partials
  gemm_mfirst<32,16,3,EPI_PART,false,true,false><<<dim3(384), 256, 0, stream>>>(
      p.Xs, p.W_x, p.Part, DI, DI, 256, 192, p);

  // R3: reduce partials -> Acat[:,0:64], bc
  r3_kernel<<<dim3(512), 256, 0, stream>>>(p);

  // G4: dt GEMM (512x2048x128, B=[W_dt|W_delta]) + softplus + y fusion
  gemm_mfirst<32,16,32,EPI_G4,false,true,true><<<dim3(512), 256, 0, stream>>>(
      p.Acat, p.W_dt, nullptr, 128, 64, 128, DI, p);

  // G5: hk = y @ W_out^T (512x1024x2048), split-K x4 -> partials
  gemm_mfirst<32,16,16,EPI_PART,false,true,false><<<dim3(1024), 256, 0, stream>>>(
      p.Yb, p.W_out, p.Part, DI, DI, 512, DM, p);

  // R5: hk = sum of 4 partials (f32)
  reduce_plain_kernel<<<dim3(512), 256, 0, stream>>>(p);
}